// Round 1
// baseline (1875.787 us; speedup 1.0000x reference)
//
#include <hip/hip_runtime.h>

#define NNODES 50000
#define NEDGES 600000
#define INCH 128
#define HIDCH 128
#define OUTCH 64
#define NGRAPHS 64

__global__ __launch_bounds__(256) void k_init_deg(float* __restrict__ deg) {
    int v = blockIdx.x * 256 + threadIdx.x;
    if (v < NNODES) deg[v] = 1.0f;   // self-loop
}

__global__ __launch_bounds__(256) void k_count_deg(const int* __restrict__ ei,
                                                   float* __restrict__ deg) {
    int e = blockIdx.x * 256 + threadIdx.x;
    if (e < NEDGES) atomicAdd(&deg[ei[NEDGES + e]], 1.0f);  // dst row
}

__global__ __launch_bounds__(256) void k_dinv(float* __restrict__ deg) {
    int v = blockIdx.x * 256 + threadIdx.x;
    if (v < NNODES) deg[v] = rsqrtf(deg[v]);   // deg >= 1 always
}

// Y[n,c] = sum_k X[n,k] * W[k,c].  X:[NNODES][128] W:[128][M] Y:[NNODES][M]
// Block = 256 threads; 16 nodes/group, 16 lanes/node (float4 over 64 cols).
// W staged in LDS as 32KB column-half; xs rows padded to 132 (bank-conflict-free).
template <int M>
__global__ __launch_bounds__(256) void k_gemm(const float* __restrict__ X,
                                              const float* __restrict__ W,
                                              float* __restrict__ Y) {
    constexpr int HALVES = M / 64;
    __shared__ float Wl[128 * 64];
    __shared__ float xs[16 * 132];
    const int tid = threadIdx.x;
    const int nofs = tid >> 4;          // 0..15 node within group
    const int c4 = (tid & 15) * 4;      // 0..60 column (float4)
    const int ngroups = (NNODES + 15) / 16;

    for (int h = 0; h < HALVES; ++h) {
        __syncthreads();
        for (int i = tid; i < 128 * 64; i += 256) {
            int k = i >> 6, cc = i & 63;
            Wl[i] = W[k * M + h * 64 + cc];
        }
        __syncthreads();
        for (int g = blockIdx.x; g < ngroups; g += gridDim.x) {
            int n0 = g * 16;
            __syncthreads();
            for (int i = tid; i < 16 * 128; i += 256) {
                int nn = i >> 7, kk = i & 127;
                int n = n0 + nn;
                xs[nn * 132 + kk] = (n < NNODES) ? X[(long)n * 128 + kk] : 0.0f;
            }
            __syncthreads();
            float4 acc = make_float4(0.f, 0.f, 0.f, 0.f);
            const float* xr = &xs[nofs * 132];
            #pragma unroll 16
            for (int k = 0; k < 128; ++k) {
                float xv = xr[k];
                float4 wv = *reinterpret_cast<const float4*>(&Wl[(k << 6) + c4]);
                acc.x = fmaf(xv, wv.x, acc.x);
                acc.y = fmaf(xv, wv.y, acc.y);
                acc.z = fmaf(xv, wv.z, acc.z);
                acc.w = fmaf(xv, wv.w, acc.w);
            }
            int n = n0 + nofs;
            if (n < NNODES)
                *reinterpret_cast<float4*>(&Y[(long)n * M + h * 64 + c4]) = acc;
        }
    }
}

// Scatter-add: acc[dst] += H[src] * dinv[src]*dinv[dst].  M/4 lanes per edge.
template <int M>
__global__ __launch_bounds__(256) void k_edge_agg(const int* __restrict__ ei,
                                                  const float* __restrict__ dinv,
                                                  const float* __restrict__ H,
                                                  float* __restrict__ acc) {
    constexpr int LPE = M / 4;
    long idx = (long)blockIdx.x * 256 + threadIdx.x;
    int e = (int)(idx / LPE);
    if (e >= NEDGES) return;
    int c4 = (int)(idx % LPE) * 4;
    int s = ei[e];
    int d = ei[NEDGES + e];
    float nrm = dinv[s] * dinv[d];
    float4 v = *reinterpret_cast<const float4*>(&H[(long)s * M + c4]);
    float* dp = &acc[(long)d * M + c4];
    atomicAdd(dp + 0, v.x * nrm);
    atomicAdd(dp + 1, v.y * nrm);
    atomicAdd(dp + 2, v.z * nrm);
    atomicAdd(dp + 3, v.w * nrm);
}

// acc = relu(acc + H*dinv^2 + b)  (layer-1 epilogue: self-loop + bias + relu)
__global__ __launch_bounds__(256) void k_finish1(const float* __restrict__ H,
                                                 float* __restrict__ acc,
                                                 const float* __restrict__ dinv,
                                                 const float* __restrict__ b) {
    long idx = (long)blockIdx.x * 256 + threadIdx.x;  // (node, 4ch) over 128 ch
    if (idx >= (long)NNODES * 32) return;
    int v = (int)(idx >> 5);
    int c4 = (int)(idx & 31) * 4;
    float dd = dinv[v];
    dd *= dd;
    float4 hv = *reinterpret_cast<const float4*>(&H[(long)v * 128 + c4]);
    float4 av = *reinterpret_cast<float4*>(&acc[(long)v * 128 + c4]);
    float4 bv = *reinterpret_cast<const float4*>(&b[c4]);
    float4 o;
    o.x = fmaxf(av.x + hv.x * dd + bv.x, 0.f);
    o.y = fmaxf(av.y + hv.y * dd + bv.y, 0.f);
    o.z = fmaxf(av.z + hv.z * dd + bv.z, 0.f);
    o.w = fmaxf(av.w + hv.w * dd + bv.w, 0.f);
    *reinterpret_cast<float4*>(&acc[(long)v * 128 + c4]) = o;
}

// out[batch[v]] += acc2[v] + H2[v]*dinv^2 + b2   (layer-2 epilogue + pool)
__global__ __launch_bounds__(256) void k_finish2_pool(const float* __restrict__ H2,
                                                      const float* __restrict__ acc2,
                                                      const float* __restrict__ dinv,
                                                      const float* __restrict__ b2,
                                                      const int* __restrict__ batch,
                                                      float* __restrict__ out) {
    long idx = (long)blockIdx.x * 256 + threadIdx.x;  // (node, 4ch) over 64 ch
    if (idx >= (long)NNODES * 16) return;
    int v = (int)(idx >> 4);
    int c4 = (int)(idx & 15) * 4;
    float dd = dinv[v];
    dd *= dd;
    float4 hv = *reinterpret_cast<const float4*>(&H2[(long)v * 64 + c4]);
    float4 av = *reinterpret_cast<const float4*>(&acc2[(long)v * 64 + c4]);
    float4 bv = *reinterpret_cast<const float4*>(&b2[c4]);
    int g = batch[v];
    float* o = &out[g * 64 + c4];
    atomicAdd(o + 0, av.x + hv.x * dd + bv.x);
    atomicAdd(o + 1, av.y + hv.y * dd + bv.y);
    atomicAdd(o + 2, av.z + hv.z * dd + bv.z);
    atomicAdd(o + 3, av.w + hv.w * dd + bv.w);
}

extern "C" void kernel_launch(void* const* d_in, const int* in_sizes, int n_in,
                              void* d_out, int out_size, void* d_ws, size_t ws_size,
                              hipStream_t stream) {
    const float* x  = (const float*)d_in[0];
    const int* ei   = (const int*)d_in[1];    // [2][NEDGES] row0=src row1=dst
    const int* batch= (const int*)d_in[2];
    const float* W1 = (const float*)d_in[3];
    const float* b1 = (const float*)d_in[4];
    const float* W2 = (const float*)d_in[5];
    const float* b2 = (const float*)d_in[6];
    float* out = (float*)d_out;

    char* ws = (char*)d_ws;
    float* deg  = (float*)ws;                                       // 200 KB
    float* bufA = (float*)(ws + (1 << 18));                         // 25.6 MB
    float* bufB = (float*)(ws + (1 << 18) + (size_t)NNODES * 128 * 4); // 25.6 MB

    hipMemsetAsync(d_out, 0, NGRAPHS * OUTCH * sizeof(float), stream);

    // degree + dinv
    k_init_deg<<<(NNODES + 255) / 256, 256, 0, stream>>>(deg);
    k_count_deg<<<(NEDGES + 255) / 256, 256, 0, stream>>>(ei, deg);
    k_dinv<<<(NNODES + 255) / 256, 256, 0, stream>>>(deg);

    // layer 1: h1 = x @ W1 ; agg ; relu(+self-loop+bias)
    k_gemm<128><<<1024, 256, 0, stream>>>(x, W1, bufA);
    hipMemsetAsync(bufB, 0, (size_t)NNODES * 128 * sizeof(float), stream);
    k_edge_agg<128><<<(int)(((long)NEDGES * 32 + 255) / 256), 256, 0, stream>>>(ei, deg, bufA, bufB);
    k_finish1<<<(int)(((long)NNODES * 32 + 255) / 256), 256, 0, stream>>>(bufA, bufB, deg, b1);

    // layer 2: h2 = h1r @ W2 ; agg ; (+self-loop+bias) ; pool
    k_gemm<64><<<1024, 256, 0, stream>>>(bufB, W2, bufA);
    hipMemsetAsync(bufB, 0, (size_t)NNODES * 64 * sizeof(float), stream);
    k_edge_agg<64><<<(int)(((long)NEDGES * 16 + 255) / 256), 256, 0, stream>>>(ei, deg, bufA, bufB);
    k_finish2_pool<<<(int)(((long)NNODES * 16 + 255) / 256), 256, 0, stream>>>(bufA, bufB, deg, b2, batch, out);
}

// Round 2
// 391.457 us; speedup vs baseline: 4.7918x; 4.7918x over previous
//
#include <hip/hip_runtime.h>

#define NNODES 50000
#define NEDGES 600000
#define INCH 128
#define HIDCH 128
#define OUTCH 64
#define NGRAPHS 64

// ---------- CSR build ----------

__global__ __launch_bounds__(256) void k_count_deg(const int* __restrict__ ei,
                                                   int* __restrict__ rp) {
    int e = blockIdx.x * 256 + threadIdx.x;
    if (e < NEDGES) atomicAdd(&rp[1 + ei[NEDGES + e]], 1);  // counts at rp[1+dst]
}

__global__ __launch_bounds__(256) void k_dinv(const int* __restrict__ rp,
                                              float* __restrict__ dinv) {
    int v = blockIdx.x * 256 + threadIdx.x;
    if (v < NNODES) dinv[v] = rsqrtf((float)rp[1 + v] + 1.0f);  // +1 self-loop
}

// single-block inclusive scan over rp[1..NNODES] (rp[0] stays 0)
__global__ __launch_bounds__(256) void k_scan(int* __restrict__ rp) {
    __shared__ int sums[256];
    const int C = (NNODES + 255) / 256;  // 196
    int t = threadIdx.x;
    int start = t * C;
    int cnt = NNODES - start;
    if (cnt < 0) cnt = 0;
    if (cnt > C) cnt = C;
    int s = 0;
    for (int i = 0; i < cnt; ++i) s += rp[1 + start + i];
    sums[t] = s;
    __syncthreads();
    for (int off = 1; off < 256; off <<= 1) {
        int v = (t >= off) ? sums[t - off] : 0;
        __syncthreads();
        sums[t] += v;
        __syncthreads();
    }
    int run = (t > 0) ? sums[t - 1] : 0;
    for (int i = 0; i < cnt; ++i) {
        run += rp[1 + start + i];
        rp[1 + start + i] = run;
    }
}

__global__ __launch_bounds__(256) void k_copy_cursor(const int* __restrict__ rp,
                                                     int* __restrict__ cur) {
    int v = blockIdx.x * 256 + threadIdx.x;
    if (v < NNODES) cur[v] = rp[v];
}

__global__ __launch_bounds__(256) void k_scatter(const int* __restrict__ ei,
                                                 int* __restrict__ cur,
                                                 int* __restrict__ csr_src) {
    int e = blockIdx.x * 256 + threadIdx.x;
    if (e >= NEDGES) return;
    int s = ei[e];
    int d = ei[NEDGES + e];
    int pos = atomicAdd(&cur[d], 1);
    csr_src[pos] = s;
}

// ---------- GEMM (fp32 vector) ----------
// Y[n,c] = sum_k X[n,k] * W[k,c].  X:[NNODES][128] W:[128][M] Y:[NNODES][M]
template <int M>
__global__ __launch_bounds__(256) void k_gemm(const float* __restrict__ X,
                                              const float* __restrict__ W,
                                              float* __restrict__ Y) {
    constexpr int HALVES = M / 64;
    __shared__ float Wl[128 * 64];
    __shared__ float xs[16 * 132];
    const int tid = threadIdx.x;
    const int nofs = tid >> 4;
    const int c4 = (tid & 15) * 4;
    const int ngroups = (NNODES + 15) / 16;

    for (int h = 0; h < HALVES; ++h) {
        __syncthreads();
        for (int i = tid; i < 128 * 64; i += 256) {
            int k = i >> 6, cc = i & 63;
            Wl[i] = W[k * M + h * 64 + cc];
        }
        __syncthreads();
        for (int g = blockIdx.x; g < ngroups; g += gridDim.x) {
            int n0 = g * 16;
            __syncthreads();
            for (int i = tid; i < 16 * 128; i += 256) {
                int nn = i >> 7, kk = i & 127;
                int n = n0 + nn;
                xs[nn * 132 + kk] = (n < NNODES) ? X[(long)n * 128 + kk] : 0.0f;
            }
            __syncthreads();
            float4 acc = make_float4(0.f, 0.f, 0.f, 0.f);
            const float* xr = &xs[nofs * 132];
            #pragma unroll 16
            for (int k = 0; k < 128; ++k) {
                float xv = xr[k];
                float4 wv = *reinterpret_cast<const float4*>(&Wl[(k << 6) + c4]);
                acc.x = fmaf(xv, wv.x, acc.x);
                acc.y = fmaf(xv, wv.y, acc.y);
                acc.z = fmaf(xv, wv.z, acc.z);
                acc.w = fmaf(xv, wv.w, acc.w);
            }
            int n = n0 + nofs;
            if (n < NNODES)
                *reinterpret_cast<float4*>(&Y[(long)n * M + h * 64 + c4]) = acc;
        }
    }
}

// ---------- CSR gather aggregation, fused epilogue ----------
// out[v] = (relu?)( sum_{s in N(v)} H[s]*dinv[s]*dinv[v] + H[v]*dinv[v]^2 + b )
template <int M, bool RELU>
__global__ __launch_bounds__(256) void k_gather(const int* __restrict__ rp,
                                                const int* __restrict__ csr_src,
                                                const float* __restrict__ dinv,
                                                const float* __restrict__ H,
                                                const float* __restrict__ bias,
                                                float* __restrict__ out) {
    constexpr int LPN = M / 4;       // lanes per node
    constexpr int NPB = 256 / LPN;   // nodes per block
    int lane = threadIdx.x % LPN;
    int grp = threadIdx.x / LPN;
    int v = blockIdx.x * NPB + grp;
    if (v >= NNODES) return;
    int c4 = lane * 4;
    float dd = dinv[v];
    float self = dd * dd;
    float4 hv = *reinterpret_cast<const float4*>(&H[(long)v * M + c4]);
    float4 acc = make_float4(hv.x * self, hv.y * self, hv.z * self, hv.w * self);
    int lo = rp[v], hi = rp[v + 1];
    for (int i = lo; i < hi; ++i) {
        int s = csr_src[i];
        float nrm = dinv[s] * dd;
        float4 m = *reinterpret_cast<const float4*>(&H[(long)s * M + c4]);
        acc.x = fmaf(m.x, nrm, acc.x);
        acc.y = fmaf(m.y, nrm, acc.y);
        acc.z = fmaf(m.z, nrm, acc.z);
        acc.w = fmaf(m.w, nrm, acc.w);
    }
    float4 bv = *reinterpret_cast<const float4*>(&bias[c4]);
    acc.x += bv.x; acc.y += bv.y; acc.z += bv.z; acc.w += bv.w;
    if (RELU) {
        acc.x = fmaxf(acc.x, 0.f);
        acc.y = fmaxf(acc.y, 0.f);
        acc.z = fmaxf(acc.z, 0.f);
        acc.w = fmaxf(acc.w, 0.f);
    }
    *reinterpret_cast<float4*>(&out[(long)v * M + c4]) = acc;
}

// ---------- per-graph pool (batch is sorted; binary-search boundaries) ----------
__device__ inline int lower_bound_i(const int* a, int n, int key) {
    int lo = 0, hi = n;
    while (lo < hi) {
        int mid = (lo + hi) >> 1;
        if (a[mid] < key) lo = mid + 1; else hi = mid;
    }
    return lo;
}

__global__ __launch_bounds__(256) void k_pool(const float* __restrict__ h2,
                                              const int* __restrict__ batch,
                                              float* __restrict__ out) {
    int g = blockIdx.x;
    int lo = lower_bound_i(batch, NNODES, g);
    int hi = lower_bound_i(batch, NNODES, g + 1);
    int ch = threadIdx.x & 63;
    int part = threadIdx.x >> 6;
    float acc = 0.f;
    for (int v = lo + part; v < hi; v += 4) acc += h2[(long)v * 64 + ch];
    __shared__ float red[256];
    red[threadIdx.x] = acc;
    __syncthreads();
    if (part == 0)
        out[g * 64 + ch] = red[ch] + red[64 + ch] + red[128 + ch] + red[192 + ch];
}

// ---------- launch ----------
extern "C" void kernel_launch(void* const* d_in, const int* in_sizes, int n_in,
                              void* d_out, int out_size, void* d_ws, size_t ws_size,
                              hipStream_t stream) {
    const float* x   = (const float*)d_in[0];
    const int* ei    = (const int*)d_in[1];
    const int* batch = (const int*)d_in[2];
    const float* W1  = (const float*)d_in[3];
    const float* b1  = (const float*)d_in[4];
    const float* W2  = (const float*)d_in[5];
    const float* b2  = (const float*)d_in[6];
    float* out = (float*)d_out;

    char* ws = (char*)d_ws;
    float* dinv   = (float*)ws;                      // 200 KB
    int*   rp     = (int*)(ws + (256 << 10));        // 50001 ints (~200 KB)
    int*   csr    = (int*)(ws + (512 << 10));        // 2.4 MB
    float* bufA   = (float*)(ws + (3u << 20));       // 25.6 MB
    float* bufB   = (float*)(ws + (3u << 20) + (size_t)NNODES * 128 * 4);
    int*   cursor = (int*)bufA;                      // alias: dead before gemm1

    // CSR build (reused by both layers)
    hipMemsetAsync(rp, 0, (NNODES + 1) * sizeof(int), stream);
    k_count_deg<<<(NEDGES + 255) / 256, 256, 0, stream>>>(ei, rp);
    k_dinv<<<(NNODES + 255) / 256, 256, 0, stream>>>(rp, dinv);
    k_scan<<<1, 256, 0, stream>>>(rp);
    k_copy_cursor<<<(NNODES + 255) / 256, 256, 0, stream>>>(rp, cursor);
    k_scatter<<<(NEDGES + 255) / 256, 256, 0, stream>>>(ei, cursor, csr);

    // layer 1
    k_gemm<128><<<1024, 256, 0, stream>>>(x, W1, bufA);
    k_gather<128, true><<<(NNODES + 7) / 8, 256, 0, stream>>>(rp, csr, dinv, bufA, b1, bufB);

    // layer 2
    k_gemm<64><<<1024, 256, 0, stream>>>(bufB, W2, bufA);
    k_gather<64, false><<<(NNODES + 15) / 16, 256, 0, stream>>>(rp, csr, dinv, bufA, b2, bufB);

    // pool
    k_pool<<<NGRAPHS, 256, 0, stream>>>(bufB, batch, out);
}

// Round 3
// 277.181 us; speedup vs baseline: 6.7674x; 1.4123x over previous
//
#include <hip/hip_runtime.h>

#define NNODES 50000
#define NEDGES 600000
#define NGRAPHS 64
#define SCAN_BLOCKS ((NNODES + 255) / 256)   // 196

// ---------- CSR build ----------

__global__ __launch_bounds__(256) void k_count_deg(const int* __restrict__ ei,
                                                   int* __restrict__ rp) {
    int e = blockIdx.x * 256 + threadIdx.x;
    if (e < NEDGES) atomicAdd(&rp[1 + ei[NEDGES + e]], 1);  // counts at rp[1+dst]
}

__global__ __launch_bounds__(256) void k_dinv(const int* __restrict__ rp,
                                              float* __restrict__ dinv) {
    int v = blockIdx.x * 256 + threadIdx.x;
    if (v < NNODES) dinv[v] = rsqrtf((float)rp[1 + v] + 1.0f);  // +1 self-loop
}

__global__ __launch_bounds__(256) void k_bsum(const int* __restrict__ rp,
                                              int* __restrict__ bsum) {
    __shared__ int red[256];
    int idx = blockIdx.x * 256 + threadIdx.x;
    red[threadIdx.x] = (idx < NNODES) ? rp[1 + idx] : 0;
    __syncthreads();
    for (int off = 128; off > 0; off >>= 1) {
        if (threadIdx.x < off) red[threadIdx.x] += red[threadIdx.x + off];
        __syncthreads();
    }
    if (threadIdx.x == 0) bsum[blockIdx.x] = red[0];
}

__global__ __launch_bounds__(256) void k_scan_bsum(int* __restrict__ bsum) {
    __shared__ int s[256];
    int t = threadIdx.x;
    s[t] = (t < SCAN_BLOCKS) ? bsum[t] : 0;
    __syncthreads();
    for (int off = 1; off < 256; off <<= 1) {
        int u = (t >= off) ? s[t - off] : 0;
        __syncthreads();
        s[t] += u;
        __syncthreads();
    }
    if (t < SCAN_BLOCKS) bsum[t] = s[t];
}

// block-scan counts, add block offset; write rowptr (inclusive) + cursor (exclusive)
__global__ __launch_bounds__(256) void k_scan_final(int* __restrict__ rp,
                                                    const int* __restrict__ bsum,
                                                    int* __restrict__ cur) {
    __shared__ int s[256];
    int t = threadIdx.x;
    int idx = blockIdx.x * 256 + t;
    int c = (idx < NNODES) ? rp[1 + idx] : 0;
    s[t] = c;
    __syncthreads();
    for (int off = 1; off < 256; off <<= 1) {
        int u = (t >= off) ? s[t - off] : 0;
        __syncthreads();
        s[t] += u;
        __syncthreads();
    }
    int incl = s[t] + (blockIdx.x ? bsum[blockIdx.x - 1] : 0);
    if (idx < NNODES) {
        rp[1 + idx] = incl;
        cur[idx] = incl - c;
    }
}

__global__ __launch_bounds__(256) void k_scatter(const int* __restrict__ ei,
                                                 int* __restrict__ cur,
                                                 int* __restrict__ csr_src) {
    int e = blockIdx.x * 256 + threadIdx.x;
    if (e >= NEDGES) return;
    int s = ei[e];
    int d = ei[NEDGES + e];
    int pos = atomicAdd(&cur[d], 1);
    csr_src[pos] = s;
}

// ---------- GEMM: Y[n,c] = dinv[n] * sum_k X[n,k]*W[k,c]  (K=128 fixed) ----------
// 64 nodes x 64 cols per block-pass; thread = (ng: 4 nodes, cg: 4 cols), 16 acc.
// xs transposed [k][n] with XOR swizzle ((k>>2)&7)<<2 : read-side conflict-free.
#define SWZ(k) ((((k) >> 2) & 7) << 2)

template <int M>
__global__ __launch_bounds__(256) void k_gemm(const float* __restrict__ X,
                                              const float* __restrict__ W,
                                              const float* __restrict__ dinv,
                                              float* __restrict__ Y) {
    constexpr int HALVES = M / 64;
    __shared__ float xs[128 * 64];   // [k][n^swz(k)]
    __shared__ float Wl[128 * 64];   // [k][c] linear
    const int tid = threadIdx.x;
    const int ng = tid & 15;         // nodes ng*4 .. ng*4+3
    const int cg = tid >> 4;         // cols  cg*4 .. cg*4+3
    const int n0 = blockIdx.x * 64;

    // stage X block (transposed+swizzled); thread u: node u>>5, k4=(u&31)*4
    for (int u = tid; u < 64 * 32; u += 256) {
        int n = u >> 5;
        int k4 = (u & 31) * 4;
        int gn = n0 + n;
        float4 xv = (gn < NNODES)
                        ? *reinterpret_cast<const float4*>(&X[(long)gn * 128 + k4])
                        : make_float4(0.f, 0.f, 0.f, 0.f);
        int col = n ^ SWZ(k4);       // swz constant over j (k4 4-aligned, j<4)
        xs[(k4 + 0) * 64 + col] = xv.x;
        xs[(k4 + 1) * 64 + col] = xv.y;
        xs[(k4 + 2) * 64 + col] = xv.z;
        xs[(k4 + 3) * 64 + col] = xv.w;
    }

    for (int h = 0; h < HALVES; ++h) {
        __syncthreads();             // xs ready / prev pass done with Wl
        for (int i = tid; i < 128 * 64; i += 256) {
            int k = i >> 6, c = i & 63;
            Wl[i] = W[k * M + h * 64 + c];
        }
        __syncthreads();
        float4 a0 = make_float4(0.f, 0.f, 0.f, 0.f);
        float4 a1 = a0, a2 = a0, a3 = a0;
        #pragma unroll 8
        for (int k = 0; k < 128; ++k) {
            float4 xv = *reinterpret_cast<const float4*>(&xs[k * 64 + ((ng * 4) ^ SWZ(k))]);
            float4 wv = *reinterpret_cast<const float4*>(&Wl[k * 64 + cg * 4]);
            a0.x = fmaf(xv.x, wv.x, a0.x); a0.y = fmaf(xv.x, wv.y, a0.y);
            a0.z = fmaf(xv.x, wv.z, a0.z); a0.w = fmaf(xv.x, wv.w, a0.w);
            a1.x = fmaf(xv.y, wv.x, a1.x); a1.y = fmaf(xv.y, wv.y, a1.y);
            a1.z = fmaf(xv.y, wv.z, a1.z); a1.w = fmaf(xv.y, wv.w, a1.w);
            a2.x = fmaf(xv.z, wv.x, a2.x); a2.y = fmaf(xv.z, wv.y, a2.y);
            a2.z = fmaf(xv.z, wv.z, a2.z); a2.w = fmaf(xv.z, wv.w, a2.w);
            a3.x = fmaf(xv.w, wv.x, a3.x); a3.y = fmaf(xv.w, wv.y, a3.y);
            a3.z = fmaf(xv.w, wv.z, a3.z); a3.w = fmaf(xv.w, wv.w, a3.w);
        }
        float4 accs[4] = {a0, a1, a2, a3};
        #pragma unroll
        for (int i = 0; i < 4; ++i) {
            int gn = n0 + ng * 4 + i;
            if (gn < NNODES) {
                float sc = dinv[gn];
                float4 a = accs[i];
                a.x *= sc; a.y *= sc; a.z *= sc; a.w *= sc;
                *reinterpret_cast<float4*>(&Y[(long)gn * M + h * 64 + cg * 4]) = a;
            }
        }
    }
}

// ---------- CSR gather: out[v] = relu?( dinv[v]*(Hs[v] + sum_s Hs[s]) + b ) ----------
template <int M, bool RELU>
__global__ __launch_bounds__(256) void k_gather(const int* __restrict__ rp,
                                                const int* __restrict__ csr_src,
                                                const float* __restrict__ dinv,
                                                const float* __restrict__ Hs,
                                                const float* __restrict__ bias,
                                                float* __restrict__ out) {
    constexpr int LPN = M / 4;
    constexpr int NPB = 256 / LPN;
    int lane = threadIdx.x % LPN;
    int grp = threadIdx.x / LPN;
    int v = blockIdx.x * NPB + grp;
    if (v >= NNODES) return;
    int c4 = lane * 4;
    float dd = dinv[v];
    float4 acc = *reinterpret_cast<const float4*>(&Hs[(long)v * M + c4]);  // self
    int lo = rp[v], hi = rp[v + 1];
    int i = lo;
    for (; i + 4 <= hi; i += 4) {
        int s0 = csr_src[i], s1 = csr_src[i + 1], s2 = csr_src[i + 2], s3 = csr_src[i + 3];
        float4 m0 = *reinterpret_cast<const float4*>(&Hs[(long)s0 * M + c4]);
        float4 m1 = *reinterpret_cast<const float4*>(&Hs[(long)s1 * M + c4]);
        float4 m2 = *reinterpret_cast<const float4*>(&Hs[(long)s2 * M + c4]);
        float4 m3 = *reinterpret_cast<const float4*>(&Hs[(long)s3 * M + c4]);
        acc.x += (m0.x + m1.x) + (m2.x + m3.x);
        acc.y += (m0.y + m1.y) + (m2.y + m3.y);
        acc.z += (m0.z + m1.z) + (m2.z + m3.z);
        acc.w += (m0.w + m1.w) + (m2.w + m3.w);
    }
    for (; i < hi; ++i) {
        int s = csr_src[i];
        float4 m = *reinterpret_cast<const float4*>(&Hs[(long)s * M + c4]);
        acc.x += m.x; acc.y += m.y; acc.z += m.z; acc.w += m.w;
    }
    float4 bv = *reinterpret_cast<const float4*>(&bias[c4]);
    acc.x = fmaf(acc.x, dd, bv.x);
    acc.y = fmaf(acc.y, dd, bv.y);
    acc.z = fmaf(acc.z, dd, bv.z);
    acc.w = fmaf(acc.w, dd, bv.w);
    if (RELU) {
        acc.x = fmaxf(acc.x, 0.f);
        acc.y = fmaxf(acc.y, 0.f);
        acc.z = fmaxf(acc.z, 0.f);
        acc.w = fmaxf(acc.w, 0.f);
    }
    *reinterpret_cast<float4*>(&out[(long)v * M + c4]) = acc;
}

// ---------- per-graph pool ----------
__device__ inline int lower_bound_i(const int* a, int n, int key) {
    int lo = 0, hi = n;
    while (lo < hi) {
        int mid = (lo + hi) >> 1;
        if (a[mid] < key) lo = mid + 1; else hi = mid;
    }
    return lo;
}

__global__ __launch_bounds__(256) void k_pool(const float* __restrict__ h2,
                                              const int* __restrict__ batch,
                                              float* __restrict__ out) {
    int g = blockIdx.x;
    int lo = lower_bound_i(batch, NNODES, g);
    int hi = lower_bound_i(batch, NNODES, g + 1);
    int ch = threadIdx.x & 63;
    int part = threadIdx.x >> 6;
    float acc = 0.f;
    for (int v = lo + part; v < hi; v += 4) acc += h2[(long)v * 64 + ch];
    __shared__ float red[256];
    red[threadIdx.x] = acc;
    __syncthreads();
    if (part == 0)
        out[g * 64 + ch] = red[ch] + red[64 + ch] + red[128 + ch] + red[192 + ch];
}

// ---------- launch ----------
extern "C" void kernel_launch(void* const* d_in, const int* in_sizes, int n_in,
                              void* d_out, int out_size, void* d_ws, size_t ws_size,
                              hipStream_t stream) {
    const float* x   = (const float*)d_in[0];
    const int* ei    = (const int*)d_in[1];
    const int* batch = (const int*)d_in[2];
    const float* W1  = (const float*)d_in[3];
    const float* b1  = (const float*)d_in[4];
    const float* W2  = (const float*)d_in[5];
    const float* b2  = (const float*)d_in[6];
    float* out = (float*)d_out;

    char* ws = (char*)d_ws;
    float* dinv = (float*)ws;                          // 200 KB
    int*   rp   = (int*)(ws + (256 << 10));            // 50001 ints
    int*   bsum = (int*)(ws + (512 << 10));            // 196 ints
    int*   csr  = (int*)(ws + (576 << 10));            // 2.4 MB
    float* bufA = (float*)(ws + (3u << 20));           // 25.6 MB
    float* bufB = (float*)(ws + (3u << 20) + (size_t)NNODES * 128 * 4);
    int*   cursor = (int*)bufA;                        // dead before gemm1 writes bufA

    // CSR build
    hipMemsetAsync(rp, 0, (NNODES + 1) * sizeof(int), stream);
    k_count_deg<<<(NEDGES + 255) / 256, 256, 0, stream>>>(ei, rp);
    k_dinv<<<(NNODES + 255) / 256, 256, 0, stream>>>(rp, dinv);
    k_bsum<<<SCAN_BLOCKS, 256, 0, stream>>>(rp, bsum);
    k_scan_bsum<<<1, 256, 0, stream>>>(bsum);
    k_scan_final<<<SCAN_BLOCKS, 256, 0, stream>>>(rp, bsum, cursor);
    k_scatter<<<(NEDGES + 255) / 256, 256, 0, stream>>>(ei, cursor, csr);

    // layer 1: Hs1 = (x@W1)*dinv ; gather+bias+relu
    k_gemm<128><<<(NNODES + 63) / 64, 256, 0, stream>>>(x, W1, dinv, bufA);
    k_gather<128, true><<<(NNODES + 7) / 8, 256, 0, stream>>>(rp, csr, dinv, bufA, b1, bufB);

    // layer 2: Hs2 = (h1@W2)*dinv ; gather+bias
    k_gemm<64><<<(NNODES + 63) / 64, 256, 0, stream>>>(bufB, W2, dinv, bufA);
    k_gather<64, false><<<(NNODES + 15) / 16, 256, 0, stream>>>(rp, csr, dinv, bufA, b2, bufB);

    // pool
    k_pool<<<NGRAPHS, 256, 0, stream>>>(bufB, batch, out);
}

// Round 4
// 161.663 us; speedup vs baseline: 11.6031x; 1.7146x over previous
//
#include <hip/hip_runtime.h>

#define NNODES 50000
#define NEDGES 600000
#define NGRAPHS 64
#define SCAN_BLOCKS ((NNODES + 255) / 256)   // 196

typedef __attribute__((ext_vector_type(8))) short short8;
typedef __attribute__((ext_vector_type(4))) float f32x4;

__device__ inline short f2bf(float f) {
    unsigned u = __float_as_uint(f);
    u = (u + 0x7fffu + ((u >> 16) & 1u)) >> 16;   // RNE
    return (short)u;
}
__device__ inline float bf2f(unsigned short s) {
    return __uint_as_float(((unsigned)s) << 16);
}
__device__ inline void addbf8(const uint4 m, float* a) {
    a[0] += __uint_as_float(m.x << 16); a[1] += __uint_as_float(m.x & 0xffff0000u);
    a[2] += __uint_as_float(m.y << 16); a[3] += __uint_as_float(m.y & 0xffff0000u);
    a[4] += __uint_as_float(m.z << 16); a[5] += __uint_as_float(m.z & 0xffff0000u);
    a[6] += __uint_as_float(m.w << 16); a[7] += __uint_as_float(m.w & 0xffff0000u);
}

// ---------- CSR build ----------

__global__ __launch_bounds__(256) void k_count_deg(const int* __restrict__ ei,
                                                   int* __restrict__ rp) {
    int e = blockIdx.x * 256 + threadIdx.x;
    if (e < NEDGES) atomicAdd(&rp[1 + ei[NEDGES + e]], 1);
}

__global__ __launch_bounds__(256) void k_dinv(const int* __restrict__ rp,
                                              float* __restrict__ dinv) {
    int v = blockIdx.x * 256 + threadIdx.x;
    if (v < NNODES) dinv[v] = rsqrtf((float)rp[1 + v] + 1.0f);
}

__global__ __launch_bounds__(256) void k_bsum(const int* __restrict__ rp,
                                              int* __restrict__ bsum) {
    __shared__ int red[256];
    int idx = blockIdx.x * 256 + threadIdx.x;
    red[threadIdx.x] = (idx < NNODES) ? rp[1 + idx] : 0;
    __syncthreads();
    for (int off = 128; off > 0; off >>= 1) {
        if (threadIdx.x < off) red[threadIdx.x] += red[threadIdx.x + off];
        __syncthreads();
    }
    if (threadIdx.x == 0) bsum[blockIdx.x] = red[0];
}

__global__ __launch_bounds__(256) void k_scan_bsum(int* __restrict__ bsum) {
    __shared__ int s[256];
    int t = threadIdx.x;
    s[t] = (t < SCAN_BLOCKS) ? bsum[t] : 0;
    __syncthreads();
    for (int off = 1; off < 256; off <<= 1) {
        int u = (t >= off) ? s[t - off] : 0;
        __syncthreads();
        s[t] += u;
        __syncthreads();
    }
    if (t < SCAN_BLOCKS) bsum[t] = s[t];
}

__global__ __launch_bounds__(256) void k_scan_final(int* __restrict__ rp,
                                                    const int* __restrict__ bsum,
                                                    int* __restrict__ cur) {
    __shared__ int s[256];
    int t = threadIdx.x;
    int idx = blockIdx.x * 256 + t;
    int c = (idx < NNODES) ? rp[1 + idx] : 0;
    s[t] = c;
    __syncthreads();
    for (int off = 1; off < 256; off <<= 1) {
        int u = (t >= off) ? s[t - off] : 0;
        __syncthreads();
        s[t] += u;
        __syncthreads();
    }
    int incl = s[t] + (blockIdx.x ? bsum[blockIdx.x - 1] : 0);
    if (idx < NNODES) {
        rp[1 + idx] = incl;
        cur[idx] = incl - c;
    }
}

__global__ __launch_bounds__(256) void k_scatter(const int* __restrict__ ei,
                                                 int* __restrict__ cur,
                                                 int* __restrict__ csr_src) {
    int e = blockIdx.x * 256 + threadIdx.x;
    if (e >= NEDGES) return;
    int s = ei[e];
    int d = ei[NEDGES + e];
    int pos = atomicAdd(&cur[d], 1);
    csr_src[pos] = s;
}

// ---------- W -> MFMA-fragment-order bf16 table ----------
// slot idx = (cf*4+ks)*64 + lane ; element j: W[ks*32+(lane>>4)*8+j][cf*16+(lane&15)]
template <int M>
__global__ __launch_bounds__(256) void k_wfrag(const float* __restrict__ W,
                                               unsigned short* __restrict__ Wf) {
    constexpr int SLOTS = (M / 16) * 4 * 64;
    int idx = blockIdx.x * 256 + threadIdx.x;
    if (idx >= SLOTS) return;
    int lane = idx & 63, ks = (idx >> 6) & 3, cf = idx >> 8;
    int c = cf * 16 + (lane & 15);
    int k0 = ks * 32 + (lane >> 4) * 8;
    unsigned t[8];
    #pragma unroll
    for (int j = 0; j < 8; ++j)
        t[j] = (unsigned short)f2bf(W[(k0 + j) * M + c]);
    uint4 o;
    o.x = t[0] | (t[1] << 16);
    o.y = t[2] | (t[3] << 16);
    o.z = t[4] | (t[5] << 16);
    o.w = t[6] | (t[7] << 16);
    ((uint4*)Wf)[idx] = o;
}

// ---------- MFMA GEMM: Y[n,c] = bf16( dinv[n] * sum_k X[n,k]*W[k,c] ), K=128 ----------
// wave owns a 64-row group (4 x 16-row MFMA frags); B frags staged in LDS per block.
template <int M, bool AF32>
__global__ __launch_bounds__(256) void k_gemm_mfma(const void* __restrict__ Xv,
                                                   const unsigned short* __restrict__ Wf,
                                                   const float* __restrict__ dinv,
                                                   unsigned short* __restrict__ Y) {
    constexpr int CF = M / 16;
    constexpr int SLOTS = CF * 4 * 64;
    __shared__ uint4 Bl[SLOTS];
    const int tid = threadIdx.x;
    for (int i = tid; i < SLOTS; i += 256) Bl[i] = ((const uint4*)Wf)[i];
    __syncthreads();

    const short8* Bs8 = (const short8*)Bl;
    const int lane = tid & 63;
    const int wave = tid >> 6;
    const int qr = lane >> 4;     // 0..3
    const int cl = lane & 15;
    const int wid = blockIdx.x * 4 + wave;
    const int nw = gridDim.x * 4;
    const int ngroups = (NNODES + 63) / 64;   // 782

    for (int g = wid; g < ngroups; g += nw) {
        const int base = g * 64;
        short8 a[4][4];
        #pragma unroll
        for (int r = 0; r < 4; ++r) {
            int arow = base + r * 16 + cl;
            bool ok = arow < NNODES;
            #pragma unroll
            for (int ks = 0; ks < 4; ++ks) {
                if (AF32) {
                    short8 v;
                    if (ok) {
                        const float* xp = (const float*)Xv + (long)arow * 128 + ks * 32 + qr * 8;
                        float4 x0 = *reinterpret_cast<const float4*>(xp);
                        float4 x1 = *reinterpret_cast<const float4*>(xp + 4);
                        v[0] = f2bf(x0.x); v[1] = f2bf(x0.y); v[2] = f2bf(x0.z); v[3] = f2bf(x0.w);
                        v[4] = f2bf(x1.x); v[5] = f2bf(x1.y); v[6] = f2bf(x1.z); v[7] = f2bf(x1.w);
                    } else {
                        v = (short8)0;
                    }
                    a[r][ks] = v;
                } else {
                    a[r][ks] = ok ? *(const short8*)((const unsigned short*)Xv +
                                                     (long)arow * 128 + ks * 32 + qr * 8)
                                  : (short8)0;
                }
            }
        }
        f32x4 acc[4][CF];
        #pragma unroll
        for (int r = 0; r < 4; ++r)
            #pragma unroll
            for (int cf = 0; cf < CF; ++cf)
                acc[r][cf] = (f32x4){0.f, 0.f, 0.f, 0.f};
        #pragma unroll
        for (int cf = 0; cf < CF; ++cf) {
            #pragma unroll
            for (int ks = 0; ks < 4; ++ks) {
                short8 b = Bs8[(cf * 4 + ks) * 64 + lane];
                #pragma unroll
                for (int r = 0; r < 4; ++r)
                    acc[r][cf] = __builtin_amdgcn_mfma_f32_16x16x32_bf16(a[r][ks], b, acc[r][cf], 0, 0, 0);
            }
        }
        // epilogue: D elem i -> row = base + r*16 + qr*4 + i, col = cf*16 + cl
        #pragma unroll
        for (int r = 0; r < 4; ++r) {
            int row0 = base + r * 16 + qr * 4;
            #pragma unroll
            for (int i = 0; i < 4; ++i) {
                int row = row0 + i;
                if (row < NNODES) {
                    float dv = dinv[row];
                    #pragma unroll
                    for (int cf = 0; cf < CF; ++cf)
                        Y[(long)row * M + cf * 16 + cl] = (unsigned short)f2bf(acc[r][cf][i] * dv);
                }
            }
        }
    }
}

// ---------- CSR gather (bf16 in/out): out[v] = relu?( dinv[v]*(Hs[v]+sum Hs[s]) + b ) ----------
template <int M, bool RELU>
__global__ __launch_bounds__(256) void k_gather(const int* __restrict__ rp,
                                                const int* __restrict__ csr_src,
                                                const float* __restrict__ dinv,
                                                const unsigned short* __restrict__ Hs,
                                                const float* __restrict__ bias,
                                                unsigned short* __restrict__ out) {
    constexpr int LPN = M / 8;       // lanes per node
    constexpr int NPB = 256 / LPN;
    int lane = threadIdx.x % LPN;
    int grp = threadIdx.x / LPN;
    int v = blockIdx.x * NPB + grp;
    if (v >= NNODES) return;
    int c8 = lane * 8;
    float dd = dinv[v];
    float a[8] = {0, 0, 0, 0, 0, 0, 0, 0};
    const uint4* Hp = (const uint4*)Hs;
    addbf8(Hp[((long)v * M + c8) >> 3], a);   // self
    int lo = rp[v], hi = rp[v + 1];
    int i = lo;
    for (; i + 4 <= hi; i += 4) {
        int s0 = csr_src[i], s1 = csr_src[i + 1], s2 = csr_src[i + 2], s3 = csr_src[i + 3];
        uint4 m0 = Hp[((long)s0 * M + c8) >> 3];
        uint4 m1 = Hp[((long)s1 * M + c8) >> 3];
        uint4 m2 = Hp[((long)s2 * M + c8) >> 3];
        uint4 m3 = Hp[((long)s3 * M + c8) >> 3];
        addbf8(m0, a); addbf8(m1, a); addbf8(m2, a); addbf8(m3, a);
    }
    for (; i < hi; ++i) {
        uint4 m = Hp[((long)csr_src[i] * M + c8) >> 3];
        addbf8(m, a);
    }
    unsigned t[8];
    #pragma unroll
    for (int j = 0; j < 8; ++j) {
        float y = fmaf(a[j], dd, bias[c8 + j]);
        if (RELU) y = fmaxf(y, 0.f);
        t[j] = (unsigned short)f2bf(y);
    }
    uint4 o;
    o.x = t[0] | (t[1] << 16);
    o.y = t[2] | (t[3] << 16);
    o.z = t[4] | (t[5] << 16);
    o.w = t[6] | (t[7] << 16);
    ((uint4*)out)[((long)v * M + c8) >> 3] = o;
}

// ---------- pool: out[g,ch] = sum over nodes of graph g (bf16 input) ----------
__device__ inline int lower_bound_i(const int* a, int n, int key) {
    int lo = 0, hi = n;
    while (lo < hi) {
        int mid = (lo + hi) >> 1;
        if (a[mid] < key) lo = mid + 1; else hi = mid;
    }
    return lo;
}

__global__ __launch_bounds__(256) void k_pool(const unsigned short* __restrict__ h2,
                                              const int* __restrict__ batch,
                                              float* __restrict__ out) {
    int g = blockIdx.x >> 4;
    int slice = blockIdx.x & 15;
    int lo = lower_bound_i(batch, NNODES, g);
    int hi = lower_bound_i(batch, NNODES, g + 1);
    int ch = threadIdx.x & 63;
    int part = threadIdx.x >> 6;
    float acc = 0.f;
    for (int v = lo + slice * 4 + part; v < hi; v += 64)
        acc += bf2f(h2[(long)v * 64 + ch]);
    __shared__ float red[256];
    red[threadIdx.x] = acc;
    __syncthreads();
    if (part == 0) {
        float s = red[ch] + red[64 + ch] + red[128 + ch] + red[192 + ch];
        atomicAdd(&out[g * 64 + ch], s);
    }
}

// ---------- launch ----------
extern "C" void kernel_launch(void* const* d_in, const int* in_sizes, int n_in,
                              void* d_out, int out_size, void* d_ws, size_t ws_size,
                              hipStream_t stream) {
    const float* x   = (const float*)d_in[0];
    const int* ei    = (const int*)d_in[1];
    const int* batch = (const int*)d_in[2];
    const float* W1  = (const float*)d_in[3];
    const float* b1  = (const float*)d_in[4];
    const float* W2  = (const float*)d_in[5];
    const float* b2  = (const float*)d_in[6];
    float* out = (float*)d_out;

    char* ws = (char*)d_ws;
    float* dinv = (float*)ws;                               // 200 KB
    int*   rp   = (int*)(ws + (256 << 10));                 // 50001 ints
    int*   bsum = (int*)(ws + (512 << 10));                 // 196 ints
    int*   csr  = (int*)(ws + (576 << 10));                 // 2.4 MB
    unsigned short* Wf1 = (unsigned short*)(ws + (3u << 20));            // 32 KB
    unsigned short* Wf2 = (unsigned short*)(ws + (3u << 20) + (64 << 10)); // 16 KB
    unsigned short* bufA = (unsigned short*)(ws + (4u << 20));           // 12.8 MB bf16
    unsigned short* bufB = (unsigned short*)(ws + (4u << 20) + (size_t)NNODES * 128 * 2);
    int* cursor = (int*)bufA;   // dead before gemm1 writes bufA

    hipMemsetAsync(d_out, 0, NGRAPHS * 64 * sizeof(float), stream);

    // CSR build
    hipMemsetAsync(rp, 0, (NNODES + 1) * sizeof(int), stream);
    k_count_deg<<<(NEDGES + 255) / 256, 256, 0, stream>>>(ei, rp);
    k_dinv<<<(NNODES + 255) / 256, 256, 0, stream>>>(rp, dinv);
    k_bsum<<<SCAN_BLOCKS, 256, 0, stream>>>(rp, bsum);
    k_scan_bsum<<<1, 256, 0, stream>>>(bsum);
    k_scan_final<<<SCAN_BLOCKS, 256, 0, stream>>>(rp, bsum, cursor);
    k_scatter<<<(NEDGES + 255) / 256, 256, 0, stream>>>(ei, cursor, csr);

    // W fragment tables
    k_wfrag<128><<<8, 256, 0, stream>>>(W1, Wf1);
    k_wfrag<64><<<4, 256, 0, stream>>>(W2, Wf2);

    // layer 1: Hs1 = bf16((x@W1)*dinv) ; gather+bias+relu -> bf16
    k_gemm_mfma<128, true><<<196, 256, 0, stream>>>(x, Wf1, dinv, bufA);
    k_gather<128, true><<<(NNODES + 15) / 16, 256, 0, stream>>>(rp, csr, dinv, bufA, b1, bufB);

    // layer 2: Hs2 = bf16((h1@W2)*dinv) ; gather+bias -> bf16
    k_gemm_mfma<64, false><<<196, 256, 0, stream>>>(bufB, Wf2, dinv, bufA);
    k_gather<64, false><<<(NNODES + 31) / 32, 256, 0, stream>>>(rp, csr, dinv, bufA, b2, bufB);

    // pool
    k_pool<<<NGRAPHS * 16, 256, 0, stream>>>(bufB, batch, out);
}

// Round 5
// 146.154 us; speedup vs baseline: 12.8344x; 1.1061x over previous
//
#include <hip/hip_runtime.h>

#define NNODES 50000
#define NEDGES 600000
#define NGRAPHS 64
#define SCAN_BLOCKS ((NNODES + 255) / 256)   // 196

typedef __attribute__((ext_vector_type(8))) short short8;
typedef __attribute__((ext_vector_type(4))) float f32x4;

__device__ inline short f2bf(float f) {
    unsigned u = __float_as_uint(f);
    u = (u + 0x7fffu + ((u >> 16) & 1u)) >> 16;   // RNE
    return (short)u;
}
__device__ inline float bf2f(unsigned short s) {
    return __uint_as_float(((unsigned)s) << 16);
}
__device__ inline void addbf8(const uint4 m, float* a) {
    a[0] += __uint_as_float(m.x << 16); a[1] += __uint_as_float(m.x & 0xffff0000u);
    a[2] += __uint_as_float(m.y << 16); a[3] += __uint_as_float(m.y & 0xffff0000u);
    a[4] += __uint_as_float(m.z << 16); a[5] += __uint_as_float(m.z & 0xffff0000u);
    a[6] += __uint_as_float(m.w << 16); a[7] += __uint_as_float(m.w & 0xffff0000u);
}

// ---------- init: W1/W2 -> MFMA frag tables, zero rp, zero out ----------
// frag slot idx = (cf*4+ks)*64+lane ; elem j: W[ks*32+(lane>>4)*8+j][cf*16+(lane&15)]
__device__ inline uint4 make_frag(const float* __restrict__ W, int M, int idx) {
    int lane = idx & 63, ks = (idx >> 6) & 3, cf = idx >> 8;
    int c = cf * 16 + (lane & 15);
    int k0 = ks * 32 + (lane >> 4) * 8;
    unsigned t[8];
    #pragma unroll
    for (int j = 0; j < 8; ++j)
        t[j] = (unsigned short)f2bf(W[(k0 + j) * M + c]);
    uint4 o;
    o.x = t[0] | (t[1] << 16);
    o.y = t[2] | (t[3] << 16);
    o.z = t[4] | (t[5] << 16);
    o.w = t[6] | (t[7] << 16);
    return o;
}

__global__ __launch_bounds__(256) void k_init(const float* __restrict__ W1,
                                              const float* __restrict__ W2,
                                              unsigned short* __restrict__ Wf1,
                                              unsigned short* __restrict__ Wf2,
                                              int* __restrict__ rp,
                                              float* __restrict__ dout) {
    int idx = blockIdx.x * 256 + threadIdx.x;       // grid = 12 blocks
    for (int i = idx; i < NNODES + 1; i += 3072) rp[i] = 0;
    for (int i = idx; i < NGRAPHS * 64; i += 3072) dout[i] = 0.f;
    if (idx < 2048) {
        ((uint4*)Wf1)[idx] = make_frag(W1, 128, idx);       // 2048 slots
    } else {
        int j = idx - 2048;                                 // 1024 slots
        ((uint4*)Wf2)[j] = make_frag(W2, 64, j);
    }
}

// ---------- CSR build ----------

__global__ __launch_bounds__(256) void k_count_deg(const int* __restrict__ ei,
                                                   int* __restrict__ rp) {
    int idx = blockIdx.x * 256 + threadIdx.x;       // 4 edges/thread
    if (idx * 4 >= NEDGES) return;
    int4 d = ((const int4*)(ei + NEDGES))[idx];
    atomicAdd(&rp[1 + d.x], 1);
    atomicAdd(&rp[1 + d.y], 1);
    atomicAdd(&rp[1 + d.z], 1);
    atomicAdd(&rp[1 + d.w], 1);
}

__global__ __launch_bounds__(256) void k_bsum(const int* __restrict__ rp,
                                              int* __restrict__ bsum) {
    __shared__ int red[256];
    int idx = blockIdx.x * 256 + threadIdx.x;
    red[threadIdx.x] = (idx < NNODES) ? rp[1 + idx] : 0;
    __syncthreads();
    for (int off = 128; off > 0; off >>= 1) {
        if (threadIdx.x < off) red[threadIdx.x] += red[threadIdx.x + off];
        __syncthreads();
    }
    if (threadIdx.x == 0) bsum[blockIdx.x] = red[0];
}

__global__ __launch_bounds__(256) void k_scan_bsum(int* __restrict__ bsum) {
    __shared__ int s[256];
    int t = threadIdx.x;
    s[t] = (t < SCAN_BLOCKS) ? bsum[t] : 0;
    __syncthreads();
    for (int off = 1; off < 256; off <<= 1) {
        int u = (t >= off) ? s[t - off] : 0;
        __syncthreads();
        s[t] += u;
        __syncthreads();
    }
    if (t < SCAN_BLOCKS) bsum[t] = s[t];
}

// scan counts -> rowptr(inclusive)+cursor(exclusive); also dinv = rsqrt(count+1)
__global__ __launch_bounds__(256) void k_scan_final(int* __restrict__ rp,
                                                    const int* __restrict__ bsum,
                                                    int* __restrict__ cur,
                                                    float* __restrict__ dinv) {
    __shared__ int s[256];
    int t = threadIdx.x;
    int idx = blockIdx.x * 256 + t;
    int c = (idx < NNODES) ? rp[1 + idx] : 0;
    s[t] = c;
    __syncthreads();
    for (int off = 1; off < 256; off <<= 1) {
        int u = (t >= off) ? s[t - off] : 0;
        __syncthreads();
        s[t] += u;
        __syncthreads();
    }
    int incl = s[t] + (blockIdx.x ? bsum[blockIdx.x - 1] : 0);
    if (idx < NNODES) {
        rp[1 + idx] = incl;
        cur[idx] = incl - c;
        dinv[idx] = rsqrtf((float)c + 1.0f);
    }
}

__global__ __launch_bounds__(256) void k_scatter(const int* __restrict__ ei,
                                                 int* __restrict__ cur,
                                                 int* __restrict__ csr_src) {
    int idx = blockIdx.x * 256 + threadIdx.x;       // 4 edges/thread
    if (idx * 4 >= NEDGES) return;
    int4 sv = ((const int4*)ei)[idx];
    int4 dv = ((const int4*)(ei + NEDGES))[idx];
    int p0 = atomicAdd(&cur[dv.x], 1); csr_src[p0] = sv.x;
    int p1 = atomicAdd(&cur[dv.y], 1); csr_src[p1] = sv.y;
    int p2 = atomicAdd(&cur[dv.z], 1); csr_src[p2] = sv.z;
    int p3 = atomicAdd(&cur[dv.w], 1); csr_src[p3] = sv.w;
}

// ---------- MFMA GEMM (layer 1): Y = bf16( dinv * (X_f32 @ W1) ), K=128, M=128 ----------
__global__ __launch_bounds__(256) void k_gemm1(const float* __restrict__ X,
                                               const unsigned short* __restrict__ Wf,
                                               const float* __restrict__ dinv,
                                               unsigned short* __restrict__ Y) {
    constexpr int CF = 8;
    constexpr int SLOTS = CF * 4 * 64;   // 2048
    __shared__ uint4 Bl[SLOTS];
    const int tid = threadIdx.x;
    for (int i = tid; i < SLOTS; i += 256) Bl[i] = ((const uint4*)Wf)[i];
    __syncthreads();

    const short8* Bs8 = (const short8*)Bl;
    const int lane = tid & 63;
    const int wave = tid >> 6;
    const int qr = lane >> 4;
    const int cl = lane & 15;
    const int wid = blockIdx.x * 4 + wave;
    const int nw = gridDim.x * 4;
    const int ngroups = (NNODES + 63) / 64;   // 782

    for (int g = wid; g < ngroups; g += nw) {
        const int base = g * 64;
        short8 a[4][4];
        #pragma unroll
        for (int r = 0; r < 4; ++r) {
            int arow = base + r * 16 + cl;
            bool ok = arow < NNODES;
            #pragma unroll
            for (int ks = 0; ks < 4; ++ks) {
                short8 v = (short8)0;
                if (ok) {
                    const float* xp = X + (long)arow * 128 + ks * 32 + qr * 8;
                    float4 x0 = *reinterpret_cast<const float4*>(xp);
                    float4 x1 = *reinterpret_cast<const float4*>(xp + 4);
                    v[0] = f2bf(x0.x); v[1] = f2bf(x0.y); v[2] = f2bf(x0.z); v[3] = f2bf(x0.w);
                    v[4] = f2bf(x1.x); v[5] = f2bf(x1.y); v[6] = f2bf(x1.z); v[7] = f2bf(x1.w);
                }
                a[r][ks] = v;
            }
        }
        f32x4 acc[4][CF];
        #pragma unroll
        for (int r = 0; r < 4; ++r)
            #pragma unroll
            for (int cf = 0; cf < CF; ++cf)
                acc[r][cf] = (f32x4){0.f, 0.f, 0.f, 0.f};
        #pragma unroll
        for (int cf = 0; cf < CF; ++cf)
            #pragma unroll
            for (int ks = 0; ks < 4; ++ks) {
                short8 b = Bs8[(cf * 4 + ks) * 64 + lane];
                #pragma unroll
                for (int r = 0; r < 4; ++r)
                    acc[r][cf] = __builtin_amdgcn_mfma_f32_16x16x32_bf16(a[r][ks], b, acc[r][cf], 0, 0, 0);
            }
        #pragma unroll
        for (int r = 0; r < 4; ++r) {
            int row0 = base + r * 16 + qr * 4;
            #pragma unroll
            for (int i = 0; i < 4; ++i) {
                int row = row0 + i;
                if (row < NNODES) {
                    float dv = dinv[row];
                    #pragma unroll
                    for (int cf = 0; cf < CF; ++cf)
                        Y[(long)row * 128 + cf * 16 + cl] = (unsigned short)f2bf(acc[r][cf][i] * dv);
                }
            }
        }
    }
}

// ---------- fused: gather layer-1 (relu+bias) -> LDS tile -> @W2 -> Hs2 bf16 ----------
// block = 64 nodes. Phase A: each wave gathers 16 nodes (4 passes x 4 groups of 16 lanes),
// writes h1 row to XOR-swizzled LDS. Phase B: wave w MFMAs rows w*16..+15 against W2 frags.
__global__ __launch_bounds__(256) void k_gather_gemm(const int* __restrict__ rp,
                                                     const int* __restrict__ csr_src,
                                                     const float* __restrict__ dinv,
                                                     const unsigned short* __restrict__ Hs,
                                                     const float* __restrict__ b1,
                                                     const unsigned short* __restrict__ Wf2,
                                                     unsigned short* __restrict__ Y) {
    __shared__ uint4 Bl[1024];                 // W2 frags, 16 KB
    __shared__ unsigned short h1[64 * 128];    // 16 KB, XOR-swizzled rows
    const int tid = threadIdx.x;
    const int lane = tid & 63;
    const int wave = tid >> 6;
    for (int i = tid; i < 1024; i += 256) Bl[i] = ((const uint4*)Wf2)[i];

    const int grp = lane >> 4;
    const int ln = lane & 15;
    const int c8 = ln * 8;
    const int base = blockIdx.x * 64;
    const uint4* Hp = (const uint4*)Hs;
    float4 bv0 = *reinterpret_cast<const float4*>(b1 + c8);
    float4 bv1 = *reinterpret_cast<const float4*>(b1 + c8 + 4);
    float bb[8] = {bv0.x, bv0.y, bv0.z, bv0.w, bv1.x, bv1.y, bv1.z, bv1.w};

    #pragma unroll
    for (int p = 0; p < 4; ++p) {
        int vloc = wave * 16 + p * 4 + grp;
        int v = base + vloc;
        uint4 o = {0u, 0u, 0u, 0u};
        if (v < NNODES) {
            float a[8] = {0, 0, 0, 0, 0, 0, 0, 0};
            float dd = dinv[v];
            addbf8(Hp[((long)v * 128 + c8) >> 3], a);   // self
            int lo = rp[v], hi = rp[v + 1];
            int i = lo;
            for (; i + 4 <= hi; i += 4) {
                int s0 = csr_src[i], s1 = csr_src[i + 1];
                int s2 = csr_src[i + 2], s3 = csr_src[i + 3];
                uint4 m0 = Hp[((long)s0 * 128 + c8) >> 3];
                uint4 m1 = Hp[((long)s1 * 128 + c8) >> 3];
                uint4 m2 = Hp[((long)s2 * 128 + c8) >> 3];
                uint4 m3 = Hp[((long)s3 * 128 + c8) >> 3];
                addbf8(m0, a); addbf8(m1, a); addbf8(m2, a); addbf8(m3, a);
            }
            for (; i < hi; ++i)
                addbf8(Hp[((long)csr_src[i] * 128 + c8) >> 3], a);
            unsigned t[8];
            #pragma unroll
            for (int j = 0; j < 8; ++j) {
                float y = fmaxf(fmaf(a[j], dd, bb[j]), 0.f);
                t[j] = (unsigned short)f2bf(y);
            }
            o.x = t[0] | (t[1] << 16);
            o.y = t[2] | (t[3] << 16);
            o.z = t[4] | (t[5] << 16);
            o.w = t[6] | (t[7] << 16);
        }
        int byte = (vloc * 256 + c8 * 2) ^ ((vloc & 7) << 4);
        *reinterpret_cast<uint4*>((char*)h1 + byte) = o;
    }
    __syncthreads();

    // Phase B: rows wave*16..+15 ; A-frag: row=wave*16+cl, k=ks*32+qr*8
    const int qr = lane >> 4;
    const int cl = lane & 15;
    const int arow = wave * 16 + cl;
    short8 afr[4];
    #pragma unroll
    for (int ks = 0; ks < 4; ++ks) {
        int byte = (arow * 256 + (ks * 32 + qr * 8) * 2) ^ ((arow & 7) << 4);
        afr[ks] = *reinterpret_cast<const short8*>((const char*)h1 + byte);
    }
    const short8* Bs8 = (const short8*)Bl;
    f32x4 acc[4];
    #pragma unroll
    for (int cf = 0; cf < 4; ++cf) acc[cf] = (f32x4){0.f, 0.f, 0.f, 0.f};
    #pragma unroll
    for (int cf = 0; cf < 4; ++cf)
        #pragma unroll
        for (int ks = 0; ks < 4; ++ks)
            acc[cf] = __builtin_amdgcn_mfma_f32_16x16x32_bf16(afr[ks], Bs8[(cf * 4 + ks) * 64 + lane], acc[cf], 0, 0, 0);
    #pragma unroll
    for (int i = 0; i < 4; ++i) {
        int row = base + wave * 16 + qr * 4 + i;
        if (row < NNODES) {
            float dv = dinv[row];
            #pragma unroll
            for (int cf = 0; cf < 4; ++cf)
                Y[(long)row * 64 + cf * 16 + cl] = (unsigned short)f2bf(acc[cf][i] * dv);
        }
    }
}

// ---------- CSR gather layer 2: out[v] = dinv[v]*(Hs[v]+sum Hs[s]) + b2 (bf16) ----------
__global__ __launch_bounds__(256) void k_gather2(const int* __restrict__ rp,
                                                 const int* __restrict__ csr_src,
                                                 const float* __restrict__ dinv,
                                                 const unsigned short* __restrict__ Hs,
                                                 const float* __restrict__ bias,
                                                 unsigned short* __restrict__ out) {
    int lane = threadIdx.x & 7;          // 8 lanes/node, 8 ch each
    int grp = threadIdx.x >> 3;
    int v = blockIdx.x * 32 + grp;
    if (v >= NNODES) return;
    int c8 = lane * 8;
    float dd = dinv[v];
    float a[8] = {0, 0, 0, 0, 0, 0, 0, 0};
    const uint4* Hp = (const uint4*)Hs;
    addbf8(Hp[((long)v * 64 + c8) >> 3], a);
    int lo = rp[v], hi = rp[v + 1];
    int i = lo;
    for (; i + 4 <= hi; i += 4) {
        int s0 = csr_src[i], s1 = csr_src[i + 1], s2 = csr_src[i + 2], s3 = csr_src[i + 3];
        uint4 m0 = Hp[((long)s0 * 64 + c8) >> 3];
        uint4 m1 = Hp[((long)s1 * 64 + c8) >> 3];
        uint4 m2 = Hp[((long)s2 * 64 + c8) >> 3];
        uint4 m3 = Hp[((long)s3 * 64 + c8) >> 3];
        addbf8(m0, a); addbf8(m1, a); addbf8(m2, a); addbf8(m3, a);
    }
    for (; i < hi; ++i)
        addbf8(Hp[((long)csr_src[i] * 64 + c8) >> 3], a);
    unsigned t[8];
    #pragma unroll
    for (int j = 0; j < 8; ++j)
        t[j] = (unsigned short)f2bf(fmaf(a[j], dd, bias[c8 + j]));
    uint4 o;
    o.x = t[0] | (t[1] << 16);
    o.y = t[2] | (t[3] << 16);
    o.z = t[4] | (t[5] << 16);
    o.w = t[6] | (t[7] << 16);
    ((uint4*)out)[((long)v * 64 + c8) >> 3] = o;
}

// ---------- pool ----------
__device__ inline int lower_bound_i(const int* a, int n, int key) {
    int lo = 0, hi = n;
    while (lo < hi) {
        int mid = (lo + hi) >> 1;
        if (a[mid] < key) lo = mid + 1; else hi = mid;
    }
    return lo;
}

__global__ __launch_bounds__(256) void k_pool(const unsigned short* __restrict__ h2,
                                              const int* __restrict__ batch,
                                              float* __restrict__ out) {
    int g = blockIdx.x >> 4;
    int slice = blockIdx.x & 15;
    int lo = lower_bound_i(batch, NNODES, g);
    int hi = lower_bound_i(batch, NNODES, g + 1);
    int ch = threadIdx.x & 63;
    int part = threadIdx.x >> 6;
    float acc = 0.f;
    for (int v = lo + slice * 4 + part; v < hi; v += 64)
        acc += bf2f(h2[(long)v * 64 + ch]);
    __shared__ float red[256];
    red[threadIdx.x] = acc;
    __syncthreads();
    if (part == 0) {
        float s = red[ch] + red[64 + ch] + red[128 + ch] + red[192 + ch];
        atomicAdd(&out[g * 64 + ch], s);
    }
}

// ---------- launch ----------
extern "C" void kernel_launch(void* const* d_in, const int* in_sizes, int n_in,
                              void* d_out, int out_size, void* d_ws, size_t ws_size,
                              hipStream_t stream) {
    const float* x   = (const float*)d_in[0];
    const int* ei    = (const int*)d_in[1];
    const int* batch = (const int*)d_in[2];
    const float* W1  = (const float*)d_in[3];
    const float* b1  = (const float*)d_in[4];
    const float* W2  = (const float*)d_in[5];
    const float* b2  = (const float*)d_in[6];
    float* out = (float*)d_out;

    char* ws = (char*)d_ws;
    float* dinv = (float*)ws;                                 // 200 KB
    int*   rp   = (int*)(ws + (256 << 10));                   // 50001 ints
    int*   bsum = (int*)(ws + (512 << 10));                   // 196 ints
    int*   csr  = (int*)(ws + (576 << 10));                   // 2.4 MB
    unsigned short* Wf1 = (unsigned short*)(ws + (3u << 20));              // 32 KB
    unsigned short* Wf2 = (unsigned short*)(ws + (3u << 20) + (64 << 10)); // 16 KB
    unsigned short* bufA = (unsigned short*)(ws + (4u << 20));             // 12.8 MB
    unsigned short* bufB = (unsigned short*)(ws + (4u << 20) + (size_t)NNODES * 128 * 2); // 6.4 MB
    int* cursor = (int*)bufA;   // dead before gemm1 writes bufA

    // init (W frags + zero rp + zero out), then CSR build
    k_init<<<12, 256, 0, stream>>>(W1, W2, Wf1, Wf2, rp, out);
    k_count_deg<<<(NEDGES / 4 + 255) / 256, 256, 0, stream>>>(ei, rp);
    k_bsum<<<SCAN_BLOCKS, 256, 0, stream>>>(rp, bsum);
    k_scan_bsum<<<1, 256, 0, stream>>>(bsum);
    k_scan_final<<<SCAN_BLOCKS, 256, 0, stream>>>(rp, bsum, cursor, dinv);
    k_scatter<<<(NEDGES / 4 + 255) / 256, 256, 0, stream>>>(ei, cursor, csr);

    // layer 1 GEMM: Hs1 = bf16((x@W1)*dinv) -> bufA
    k_gemm1<<<196, 256, 0, stream>>>(x, Wf1, dinv, bufA);

    // fused: gather1(+bias+relu) -> @W2 -> Hs2 = bf16(dinv*(h1@W2)) -> bufB
    k_gather_gemm<<<(NNODES + 63) / 64, 256, 0, stream>>>(rp, csr, dinv, bufA, b1, Wf2, bufB);

    // gather2 (+bias) -> out2 (reuse bufA region)
    k_gather2<<<(NNODES + 31) / 32, 256, 0, stream>>>(rp, csr, dinv, bufB, b2, bufA);

    // pool
    k_pool<<<NGRAPHS * 16, 256, 0, stream>>>(bufA, batch, out);
}